// Round 2
// baseline (177.632 us; speedup 1.0000x reference)
//
#include <hip/hip_runtime.h>

// Causal self-attention fwd: B=2,T=2048,C=1024,H=16,D=64, scale=0.1/sqrt(D)
// prep (cast x + transpose weights); qkv GEMM = 256x256 8-phase schedule
// (T2 global-side XOR swizzle + T3/T4 counted vmcnt(4)/phase + T5 setprio;
// provably race-free staging: tile kt stages (kt+1, ht_ph) into the OTHER
// buffer only -- every staged region's last read is >=1 barrier in the past;
// V written PRE-TRANSPOSED, q pre-scaled by SCALE*log2e); flash attn
// (S^T = K*Q^T, P in registers, K/V staged via global_load_lds w/ global-side
// XOR swizzle, double-buffered, m=0 softmax, XCD-affine CU-balanced grid);
// proj GEMM (128x64 m97-structure).

#define Bz 2
#define Tz 2048
#define Cz 1024
#define Hz 16
#define Dz 64
// SCALE * log2(e): q pre-scaled so attn does p = exp2(S) directly
#define QSCALE 0.01803368801111437f

typedef unsigned short u16;
typedef short bf16x4 __attribute__((ext_vector_type(4)));
typedef short bf16x8 __attribute__((ext_vector_type(8)));
typedef float f32x4 __attribute__((ext_vector_type(4)));

#define MFMA32(A, B, C) __builtin_amdgcn_mfma_f32_16x16x32_bf16(A, B, C, 0, 0, 0)

// K=16 bf16 MFMA. Guard with __HIP_DEVICE_COMPILE__ (R8 lesson: __has_builtin
// is unreliable for aux-target builtins in the host pass).
__device__ inline f32x4 mfma16(bf16x4 a, bf16x4 b, f32x4 c) {
#if defined(__HIP_DEVICE_COMPILE__)
  return __builtin_amdgcn_mfma_f32_16x16x16bf16_1k(a, b, c, 0, 0, 0);
#else
  return c;  // host pass placeholder, never executed
#endif
}

__device__ inline u16 f2bf(float f) {  // round-half-up: 2 VALU, <=0.5 ulp
  return (u16)((__float_as_uint(f) + 0x8000u) >> 16);
}

__device__ inline float fexp2(float x) {  // raw v_exp_f32 (R6-proven guard)
#if __has_builtin(__builtin_amdgcn_exp2f)
  return __builtin_amdgcn_exp2f(x);
#else
  return exp2f(x);
#endif
}

__device__ inline void gl_lds16(const u16* g, u16* l) {
  __builtin_amdgcn_global_load_lds(
      (const __attribute__((address_space(1))) void*)g,
      (__attribute__((address_space(3))) void*)l, 16, 0, 0);
}

// ------------- prep: cast x->bf16 + transpose/cast both weights -------------
#define NCAST 4096   // (4096*1024/4)/256
#define NTA   3072   // (3072/32)*(1024/32)
__global__ __launch_bounds__(256) void prep_kernel(const float* __restrict__ x,
                                                   const float* __restrict__ wa,
                                                   const float* __restrict__ wp,
                                                   u16* __restrict__ xb,
                                                   u16* __restrict__ waT,
                                                   u16* __restrict__ wpT) {
  const int bx = blockIdx.x, t = threadIdx.x;
  if (bx < NCAST) {
    int i = bx * 256 + t;
    float4 v = ((const float4*)x)[i];
    ushort4 o = {f2bf(v.x), f2bf(v.y), f2bf(v.z), f2bf(v.w)};
    ((ushort4*)xb)[i] = o;
    return;
  }
  __shared__ float tile[32][33];
  const float* W;
  u16* WT;
  int N, idx;
  if (bx < NCAST + NTA) {
    W = wa; WT = waT; N = 3 * Cz; idx = bx - NCAST;
  } else {
    W = wp; WT = wpT; N = Cz; idx = bx - NCAST - NTA;
  }
  const int n0 = (idx % (N / 32)) * 32, k0 = (idx / (N / 32)) * 32;
  const int tx = t & 31, ty = t >> 5;  // (32, 8)
#pragma unroll
  for (int i = 0; i < 4; ++i)
    tile[ty + 8 * i][tx] = W[(size_t)(k0 + ty + 8 * i) * N + n0 + tx];
  __syncthreads();
#pragma unroll
  for (int i = 0; i < 4; ++i)
    WT[(size_t)(n0 + ty + 8 * i) * Cz + k0 + tx] = f2bf(tile[tx][ty + 8 * i]);
}

// ---------------- qkv GEMM: 256x256 tile, BK=64, 8 waves, 8-phase ----------------
// Per K-tile: 4 quadrant-phases (A-half qa = ph>>1, B-half qb = ph&1).
// Wave (wm,wn) owns 64 rows of each A-half x 32 cols of each B-half ->
// per phase 16 MFMAs, 12 ds_read_b128.
//
// STAGING LEDGER (race-free by construction):
//   tile kt, phase p stages (kt+1, ht_p) into buffer (kt+1)&1 = 1-cb.
//   Region ht_p of 1-cb was last READ during tile kt-1 (ht0@ph1, ht1@ph2,
//   ht2@ph3, ht3@ph3) -> >=1 s_barrier separates last read from stage issue.
//   Reads by phase (buffer cb): ph0:{ht0,ht1} ph1:{ht0,ht2} ph2:{ht3,ht1}
//   ph3:{ht3,ht2}.  In-order vmcnt, 2 loads/half-tile, 1 stage/phase:
//   uniform s_waitcnt vmcnt(4) at each phase end retires the half-tile staged
//   2 phases earlier == exactly when first needed (ht2 by ph1, ht3 by ph2,
//   next tile's ht0,ht1 by next ph0).  Steady-state floor = 4 (never 0).
//   Tail (kt == KT-1, no stages): vmcnt(2) @ph0, vmcnt(0) @ph1.
// Epilogue: bias; q cols pre-scaled; V cols stored transposed to vT[d][s].
__global__ __launch_bounds__(512, 2) void gemm_qkv(const u16* __restrict__ A,
                                                   const u16* __restrict__ BT,
                                                   const float* __restrict__ bias,
                                                   u16* __restrict__ Cout,
                                                   u16* __restrict__ vTout) {
  constexpr int K = Cz;        // 1024
  constexpr int N = 3 * Cz;    // 3072
  constexpr int KT = K / 64;   // 16 K-tiles
  // [buf][ht][128*64] bf16: ht0 = A rows 0-127, ht1 = B rows 0-127,
  // ht2 = B rows 128-255, ht3 = A rows 128-255.  128 KiB total.
  __shared__ __align__(16) u16 L[2][4][128 * 64];

  const int t = threadIdx.x;
  const int wave = t >> 6, lane = t & 63;
  const int lm = lane & 15, lg = lane >> 4;
  const int wm = wave >> 2, wn = wave & 3;  // 2M x 4N wave grid
  const int m0 = blockIdx.y * 256, n0 = blockIdx.x * 256;

  // gl_lds: LDS base wave-uniform (m104); lane l lands at base + 16B*l.
  // wave stages rows [8w,8w+8) (+64) per half-tile; global addr carries the
  // XOR swizzle (LDS[row][seg s] = global[row][seg s^(row&7)]).
  const int srow = 8 * wave + (lane >> 3);            // global row 0..63
  const int sgl = ((lane & 7) ^ (lane >> 3)) * 8;     // swizzled col (u16)

  auto stage_ht = [&](int kt, int ht) {
    const bool isA = (ht == 0) || (ht == 3);
    const int half = (ht >= 2) ? 1 : 0;
    const u16* src =
        (isA ? A + (size_t)(m0 + half * 128 + srow) * K
             : BT + (size_t)(n0 + half * 128 + srow) * K) +
        (size_t)kt * 64 + sgl;
    u16* dst = &L[kt & 1][ht][(8 * wave) * 64];
    gl_lds16(src, dst);
    gl_lds16(src + (size_t)64 * K, dst + 64 * 64);  // rows +64
  };

  f32x4 acc[2][2][4][2];
#pragma unroll
  for (int qa = 0; qa < 2; ++qa)
#pragma unroll
    for (int qb = 0; qb < 2; ++qb)
#pragma unroll
      for (int mt = 0; mt < 4; ++mt)
#pragma unroll
        for (int nt = 0; nt < 2; ++nt)
#pragma unroll
          for (int i = 0; i < 4; ++i) acc[qa][qb][mt][nt][i] = 0.f;

  // prologue: stage tile0 ht0..3 (8 loads/wave); vmcnt(4) -> ht0,ht1 resident.
#pragma unroll
  for (int i = 0; i < 4; ++i) stage_ht(0, i);
  asm volatile("s_waitcnt vmcnt(4)" ::: "memory");
  __builtin_amdgcn_s_barrier();

  for (int kt = 0; kt < KT; ++kt) {
    const int cb = kt & 1;
#pragma unroll
    for (int ph = 0; ph < 4; ++ph) {
      const int qa = ph >> 1, qb = ph & 1;
      // ds-load this quadrant's frags (reads un-swizzle: seg ^ (row&7))
      bf16x8 af[4][2], bfr[2][2];
#pragma unroll
      for (int mt = 0; mt < 4; ++mt)
#pragma unroll
        for (int h = 0; h < 2; ++h)
          af[mt][h] = *(const bf16x8*)&L[cb][qa ? 3 : 0]
              [(64 * wm + 16 * mt + lm) * 64 + (((lg + 4 * h) ^ (lm & 7)) << 3)];
#pragma unroll
      for (int nt = 0; nt < 2; ++nt)
#pragma unroll
        for (int h = 0; h < 2; ++h)
          bfr[nt][h] = *(const bf16x8*)&L[cb][qb ? 2 : 1]
              [(32 * wn + 16 * nt + lm) * 64 + (((lg + 4 * h) ^ (lm & 7)) << 3)];
      // stage (kt+1, ht_ph) into the other buffer (region idle since kt-1)
      if (kt + 1 < KT) stage_ht(kt + 1, ph);
      __builtin_amdgcn_s_barrier();
      asm volatile("s_waitcnt lgkmcnt(0)" ::: "memory");
      __builtin_amdgcn_s_setprio(1);
#pragma unroll
      for (int mt = 0; mt < 4; ++mt)
#pragma unroll
        for (int nt = 0; nt < 2; ++nt) {
          acc[qa][qb][mt][nt] = MFMA32(af[mt][0], bfr[nt][0], acc[qa][qb][mt][nt]);
          acc[qa][qb][mt][nt] = MFMA32(af[mt][1], bfr[nt][1], acc[qa][qb][mt][nt]);
        }
      __builtin_amdgcn_s_setprio(0);
      // retire the half-tile staged 2 phases ago (in-order vmcnt).
      if (kt < KT - 1)
        asm volatile("s_waitcnt vmcnt(4)" ::: "memory");
      else if (ph == 0)
        asm volatile("s_waitcnt vmcnt(2)" ::: "memory");
      else
        asm volatile("s_waitcnt vmcnt(0)" ::: "memory");
      __builtin_amdgcn_s_barrier();
    }
  }

  // epilogue: bias + q-scale; V cols -> transposed vT store
#pragma unroll
  for (int qa = 0; qa < 2; ++qa)
#pragma unroll
    for (int qb = 0; qb < 2; ++qb)
#pragma unroll
      for (int nt = 0; nt < 2; ++nt) {
        const int gc = n0 + 128 * qb + 32 * wn + 16 * nt + lm;
        const float bv = bias[gc];
        if (gc >= 2 * Cz) {  // V column (block-uniform branch)
          const int dg = gc - 2 * Cz;
#pragma unroll
          for (int mt = 0; mt < 4; ++mt) {
            const int gr0 = m0 + 128 * qa + 64 * wm + 16 * mt + 4 * lg;
            const int bb = gr0 >> 11, s0 = gr0 & 2047;
            const f32x4 av = acc[qa][qb][mt][nt];
            ushort4 o = {f2bf(av[0] + bv), f2bf(av[1] + bv),
                         f2bf(av[2] + bv), f2bf(av[3] + bv)};
            *(ushort4*)(vTout + (((size_t)(bb * 1024 + dg)) << 11) + s0) = o;
          }
        } else {
          const float sc = (gc < Cz) ? QSCALE : 1.f;
#pragma unroll
          for (int mt = 0; mt < 4; ++mt)
#pragma unroll
            for (int i = 0; i < 4; ++i) {
              const int gr = m0 + 128 * qa + 64 * wm + 16 * mt + 4 * lg + i;
              Cout[(size_t)gr * N + gc] = f2bf((acc[qa][qb][mt][nt][i] + bv) * sc);
            }
        }
      }
}

// ---------- C[M][N] = A[M][K]*BT[N][K]^T + bias; 128xTN tile, BK=64 ----------
// (kept for the proj GEMM: N=1024 would underfill the 256^2 template's grid)
template <bool OUT_BF16, int TN, bool VSPLIT>
__global__ __launch_bounds__(256) void gemm_bt(const u16* __restrict__ A,
                                               const u16* __restrict__ BT,
                                               const float* __restrict__ bias,
                                               void* __restrict__ Cout,
                                               u16* __restrict__ vTout,
                                               int M, int N, int K,
                                               int qcols, float qscale) {
  __shared__ __align__(16) u16 As[128 * 64];
  __shared__ __align__(16) u16 Bs[TN * 64];
  constexpr int NT = TN / 32;
  const int t = threadIdx.x;
  const int wave = t >> 6, lane = t & 63;
  const int lm = lane & 15, lg = lane >> 4;
  const int wm = wave >> 1, wn = wave & 1;
  const int m0 = blockIdx.y * 128, n0 = blockIdx.x * TN;

  const int lrow = lane >> 3;                 // 0..7
  const int gseg = (lane & 7) ^ lrow;         // global col-seg (XOR swizzle)
  const size_t a_base = (size_t)(m0 + 32 * wave + lrow) * K + gseg * 8;
  u16* const a_lds = &As[(32 * wave) * 64];
  const size_t b_base = (size_t)(n0 + (TN / 4) * wave + lrow) * K + gseg * 8;
  u16* const b_lds = &Bs[((TN / 4) * wave) * 64];

  f32x4 acc[4][NT];
#pragma unroll
  for (int mt = 0; mt < 4; ++mt)
#pragma unroll
    for (int nt = 0; nt < NT; ++nt)
#pragma unroll
      for (int i = 0; i < 4; ++i) acc[mt][nt][i] = 0.f;

  for (int k0 = 0; k0 < K; k0 += 64) {
    __syncthreads();
#pragma unroll
    for (int i = 0; i < 4; ++i)
      gl_lds16(A + a_base + (size_t)(8 * i) * K + k0, a_lds + i * 8 * 64);
#pragma unroll
    for (int i = 0; i < NT; ++i)
      gl_lds16(BT + b_base + (size_t)(8 * i) * K + k0, b_lds + i * 8 * 64);
    __syncthreads();

#pragma unroll
    for (int h = 0; h < 2; ++h) {
      const int rs = ((lg + 4 * h) ^ (lm & 7)) * 8;
      bf16x8 af[4], bfr[NT];
#pragma unroll
      for (int mt = 0; mt < 4; ++mt)
        af[mt] = *(const bf16x8*)&As[(64 * wm + 16 * mt + lm) * 64 + rs];
#pragma unroll
      for (int nt = 0; nt < NT; ++nt)
        bfr[nt] = *(const bf16x8*)&Bs[((TN / 2) * wn + 16 * nt + lm) * 64 + rs];
#pragma unroll
      for (int mt = 0; mt < 4; ++mt)
#pragma unroll
        for (int nt = 0; nt < NT; ++nt)
          acc[mt][nt] = MFMA32(af[mt], bfr[nt], acc[mt][nt]);
    }
  }

#pragma unroll
  for (int nt = 0; nt < NT; ++nt) {
    int gc = n0 + (TN / 2) * wn + 16 * nt + lm;
    float bv = bias[gc];
    if (VSPLIT && gc >= 2 * Cz) {
      // V column -> transposed store: vTout[(b*1024 + dg)][s0..s0+3]
      const int dg = gc - 2 * Cz;
#pragma unroll
      for (int mt = 0; mt < 4; ++mt) {
        const int gr0 = m0 + 64 * wm + 16 * mt + 4 * lg;
        const int bb = gr0 >> 11, s0 = gr0 & 2047;
        ushort4 o = {f2bf(acc[mt][nt][0] + bv), f2bf(acc[mt][nt][1] + bv),
                     f2bf(acc[mt][nt][2] + bv), f2bf(acc[mt][nt][3] + bv)};
        *(ushort4*)(vTout + (((size_t)(bb * 1024 + dg)) << 11) + s0) = o;
      }
      continue;
    }
    float sc = (gc < qcols) ? qscale : 1.f;
#pragma unroll
    for (int mt = 0; mt < 4; ++mt) {
#pragma unroll
      for (int i = 0; i < 4; ++i) {
        int gr = m0 + 64 * wm + 16 * mt + 4 * lg + i;
        float v = (acc[mt][nt][i] + bv) * sc;
        if (OUT_BF16)
          ((u16*)Cout)[(size_t)gr * N + gc] = f2bf(v);
        else
          ((float*)Cout)[(size_t)gr * N + gc] = v;
      }
    }
  }
}

// ---------------- flash attention, MFMA bf16, m=0 softmax, S^T ----------------
// 1D grid 1024: x = qtp*32+bh (XCD-affine); balanced qt = qtp<16?qtp:47-qtp.
// Wave w owns Q-rows [64qt+16w,+16). S^T = K*Q^T; p = exp2(S^T) packed
// in-register as 16x16x16-MFMA A-frag (P never touches LDS). K and V staged
// with global_load_lds (w=16) into unpadded stride-64 LDS; conflicts killed
// by XOR swizzle on the GLOBAL address (seg_g = seg_l ^ (row&7)) -- legal
// since gl_lds global addrs are per-lane, LDS base wave-uniform (m104).
// Frag reads un-swizzle; K b128 and V b64 patterns are bank-minimal (free).
// Double-buffered, ONE barrier/stage; gl_lds for kt+1 issued right after the
// barrier. V comes from pre-transposed vT[d][s] (written by qkv GEMM).
__global__ __launch_bounds__(256) void attn_kernel(const u16* __restrict__ qkv,
                                                   const u16* __restrict__ vT,
                                                   u16* __restrict__ yb) {
  __shared__ __align__(16) u16 KsL[2][64 * 64];
  __shared__ __align__(16) u16 VtL[2][64 * 64];

  const int t = threadIdx.x;
  const int wave = t >> 6, lane = t & 63;
  const int lm = lane & 15, lg = lane >> 4;
  const int x = blockIdx.x;
  const int bh = x & 31, qtp = x >> 5;
  const int qt = (qtp < 16) ? qtp : 47 - qtp;  // CU-balanced map
  const int b = bh >> 4, h = bh & 15;
  const int q0 = qt * 64;
  const size_t rowstride = 3 * Cz;
  const u16* qbase = qkv + (size_t)b * Tz * rowstride + h * Dz;
  const u16* vTbh = vT + ((size_t)(b * Hz + h) * Dz) * Tz;  // [64][2048]

  // Q fragments: B-operand of the S^T MFMA (lane lm = q-col, elems = d)
  bf16x8 qf[2];
  {
    const u16* qrow = qbase + (size_t)(q0 + wave * 16 + lm) * rowstride + (lg << 3);
    qf[0] = *(const bf16x8*)qrow;
    qf[1] = *(const bf16x8*)(qrow + 32);
  }

  float psum = 0.f;  // l for q = 16*wave + lm (partial over this lane's s)
  f32x4 Oa[4];       // Oa[dt][r] = O[q=16w+4lg+r][d=16dt+lm]
#pragma unroll
  for (int i = 0; i < 4; ++i)
#pragma unroll
    for (int j = 0; j < 4; ++j) Oa[i][j] = 0.f;

  // staging: wave w stages rows [16w,16w+16) of both K and V tiles.
  // lane i -> row +(i>>3), LDS seg i&7 holding GLOBAL seg (i&7)^(i>>3).
  const int srow = lane >> 3;              // 0..7
  const int sgl = ((lane & 7) ^ srow) * 8; // global col offset (swizzled)
  const u16* kstg = qbase + Cz + (size_t)(16 * wave + srow) * rowstride + sgl;
  const u16* vstg = vTbh + (size_t)(16 * wave + srow) * Tz + sgl;

  auto stage_issue = [&](int kt, int buf) {
#pragma unroll
    for (int c2 = 0; c2 < 2; ++c2) {
      gl_lds16(kstg + (size_t)(8 * c2) * rowstride + (size_t)(64 * kt) * rowstride,
               &KsL[buf][(16 * wave + 8 * c2) * 64]);
      gl_lds16(vstg + (size_t)(8 * c2) * Tz + 64 * kt,
               &VtL[buf][(16 * wave + 8 * c2) * 64]);
    }
  };

  stage_issue(0, 0);  // prologue; first barrier drains it

  for (int kt = 0; kt <= qt; ++kt) {
    __syncthreads();  // buf(kt&1) loads drained; prior readers of other buf done
    const int cb = kt & 1;
    if (kt + 1 <= qt) stage_issue(kt + 1, 1 - cb);

    // ---- S^T = K Q^T (pre-scaled): lane gets s=16c+4lg+r, q=16w+lm ----
    f32x4 S[4];
#pragma unroll
    for (int c = 0; c < 4; ++c) {
      const int rb = (16 * c + lm) * 64;
      bf16x8 k0 = *(const bf16x8*)&KsL[cb][rb + ((lg ^ (lm & 7)) << 3)];
      bf16x8 k1 = *(const bf16x8*)&KsL[cb][rb + (((lg + 4) ^ (lm & 7)) << 3)];
      f32x4 s;
#pragma unroll
      for (int i = 0; i < 4; ++i) s[i] = 0.f;
      s = MFMA32(k0, qf[0], s);
      s = MFMA32(k1, qf[1], s);
      S[c] = s;
    }

    // ---- p = exp2(S^T), diag mask, accumulate l, pack A-frags in-reg ----
    const bool diag = (kt == qt);
    const int qloc = 16 * wave + lm;
    bf16x4 pf[4];
#pragma unroll
    for (int c = 0; c < 4; ++c) {
#pragma unroll
      for (int r = 0; r < 4; ++r) {
        float p = fexp2(S[c][r]);
        if (diag && (c * 16 + 4 * lg + r) > qloc) p = 0.f;
        psum += p;
        pf[c][r] = (short)f2bf(p);
      }
    }

    // ---- O += P V: K=16 MFMAs, A=pf (registers), B from VtL[d][s] ----
#pragma unroll
    for (int dt = 0; dt < 4; ++dt) {
      const int rb = (16 * dt + lm) * 64;
#pragma unroll
      for (int c = 0; c < 4; ++c) {
        const int off = (((2 * c + (lg >> 1)) ^ (lm & 7)) << 3) + 4 * (lg & 1);
        bf16x4 vfr = *(const bf16x4*)&VtL[cb][rb + off];
        Oa[dt] = mfma16(pf[c], vfr, Oa[dt]);
      }
    }
  }

  // ---- epilogue: l-reduce over lg, redistribute inv, bounce via KsL[0] ----
  float s = psum;
  s += __shfl_xor(s, 16);
  s += __shfl_xor(s, 32);
  const float linv = 1.f / s;  // l(q=16w+lm), valid at all lg
  float invq[4];
#pragma unroll
  for (int r = 0; r < 4; ++r)
    invq[r] = __shfl(linv, 20 * lg + r);  // lane with lm = 4lg+r (same lg)
  __syncthreads();  // all KsL/VtL readers done; reuse KsL[0] as store bounce
#pragma unroll
  for (int dt = 0; dt < 4; ++dt)
#pragma unroll
    for (int r = 0; r < 4; ++r)
      KsL[0][(16 * wave + 4 * lg + r) * 64 + 16 * dt + lm] =
          f2bf(Oa[dt][r] * invq[r]);
  __syncthreads();
  {
    const int row = lane >> 2, seg = lane & 3;
    const uint4* src = (const uint4*)&KsL[0][(16 * wave + row) * 64 + seg * 16];
    uint4 v0 = src[0];
    uint4 v1 = src[1];
    u16* dst = yb + (size_t)(b * Tz + q0 + 16 * wave + row) * Cz + h * Dz + seg * 16;
    *(uint4*)dst = v0;
    *(uint4*)(dst + 8) = v1;
  }
}

extern "C" void kernel_launch(void* const* d_in, const int* in_sizes, int n_in,
                              void* d_out, int out_size, void* d_ws, size_t ws_size,
                              hipStream_t stream) {
  const float* x      = (const float*)d_in[0];
  const float* w_attn = (const float*)d_in[1];
  const float* b_attn = (const float*)d_in[2];
  const float* w_proj = (const float*)d_in[3];
  const float* b_proj = (const float*)d_in[4];

  char* ws = (char*)d_ws;
  u16* xb   = (u16*)(ws);                        //  8 MB: x bf16 [4096,1024]
  u16* waT  = (u16*)(ws + (8ull << 20));         //  6 MB: w_attn^T bf16 [3072,1024]
  u16* wpT  = (u16*)(ws + (14ull << 20));        //  2 MB: w_proj^T bf16 [1024,1024]
  u16* qkvb = (u16*)(ws + (16ull << 20));        // 24 MB: qkv bf16 (q pre-scaled; V cols unused)
  u16* yb   = (u16*)(ws + (40ull << 20));        //  8 MB: y bf16 [4096,1024]
  u16* vTt  = (u16*)(ws + (48ull << 20));        //  8 MB: V^T bf16 [2*16*64][2048]

  const int M = Bz * Tz;  // 4096

  prep_kernel<<<NCAST + NTA + 1024, 256, 0, stream>>>(x, w_attn, w_proj, xb, waT, wpT);
  gemm_qkv<<<dim3(3 * Cz / 256, M / 256), 512, 0, stream>>>(xb, waT, b_attn, qkvb, vTt);
  attn_kernel<<<1024, 256, 0, stream>>>(qkvb, vTt, yb);
  gemm_bt<false, 64, false><<<dim3(Cz / 64, M / 128), 256, 0, stream>>>(
      yb, wpT, b_proj, d_out, nullptr, M, Cz, Cz, 0, 1.f);
}

// Round 3
// 176.374 us; speedup vs baseline: 1.0071x; 1.0071x over previous
//
#include <hip/hip_runtime.h>

// Causal self-attention fwd: B=2,T=2048,C=1024,H=16,D=64, scale=0.1/sqrt(D)
// prep (cast x + transpose weights); qkv GEMM = 256x256 8-phase schedule,
// R3: B-quadrants register-resident (24 ds_read/K-tile, was 48), stage-all
// burst at ph0 with relaxed vmcnt ledger {10,8,-,4} (>=4-phase load window),
// XCD-affine block swizzle (2 grid rows per XCD). flash attn + proj unchanged.

#define Bz 2
#define Tz 2048
#define Cz 1024
#define Hz 16
#define Dz 64
// SCALE * log2(e): q pre-scaled so attn does p = exp2(S) directly
#define QSCALE 0.01803368801111437f

typedef unsigned short u16;
typedef short bf16x4 __attribute__((ext_vector_type(4)));
typedef short bf16x8 __attribute__((ext_vector_type(8)));
typedef float f32x4 __attribute__((ext_vector_type(4)));

#define MFMA32(A, B, C) __builtin_amdgcn_mfma_f32_16x16x32_bf16(A, B, C, 0, 0, 0)

// K=16 bf16 MFMA. Guard with __HIP_DEVICE_COMPILE__ (R8 lesson: __has_builtin
// is unreliable for aux-target builtins in the host pass).
__device__ inline f32x4 mfma16(bf16x4 a, bf16x4 b, f32x4 c) {
#if defined(__HIP_DEVICE_COMPILE__)
  return __builtin_amdgcn_mfma_f32_16x16x16bf16_1k(a, b, c, 0, 0, 0);
#else
  return c;  // host pass placeholder, never executed
#endif
}

__device__ inline u16 f2bf(float f) {  // round-half-up: 2 VALU, <=0.5 ulp
  return (u16)((__float_as_uint(f) + 0x8000u) >> 16);
}

__device__ inline float fexp2(float x) {  // raw v_exp_f32 (R6-proven guard)
#if __has_builtin(__builtin_amdgcn_exp2f)
  return __builtin_amdgcn_exp2f(x);
#else
  return exp2f(x);
#endif
}

__device__ inline void gl_lds16(const u16* g, u16* l) {
  __builtin_amdgcn_global_load_lds(
      (const __attribute__((address_space(1))) void*)g,
      (__attribute__((address_space(3))) void*)l, 16, 0, 0);
}

// ------------- prep: cast x->bf16 + transpose/cast both weights -------------
#define NCAST 4096   // (4096*1024/4)/256
#define NTA   3072   // (3072/32)*(1024/32)
__global__ __launch_bounds__(256) void prep_kernel(const float* __restrict__ x,
                                                   const float* __restrict__ wa,
                                                   const float* __restrict__ wp,
                                                   u16* __restrict__ xb,
                                                   u16* __restrict__ waT,
                                                   u16* __restrict__ wpT) {
  const int bx = blockIdx.x, t = threadIdx.x;
  if (bx < NCAST) {
    int i = bx * 256 + t;
    float4 v = ((const float4*)x)[i];
    ushort4 o = {f2bf(v.x), f2bf(v.y), f2bf(v.z), f2bf(v.w)};
    ((ushort4*)xb)[i] = o;
    return;
  }
  __shared__ float tile[32][33];
  const float* W;
  u16* WT;
  int N, idx;
  if (bx < NCAST + NTA) {
    W = wa; WT = waT; N = 3 * Cz; idx = bx - NCAST;
  } else {
    W = wp; WT = wpT; N = Cz; idx = bx - NCAST - NTA;
  }
  const int n0 = (idx % (N / 32)) * 32, k0 = (idx / (N / 32)) * 32;
  const int tx = t & 31, ty = t >> 5;  // (32, 8)
#pragma unroll
  for (int i = 0; i < 4; ++i)
    tile[ty + 8 * i][tx] = W[(size_t)(k0 + ty + 8 * i) * N + n0 + tx];
  __syncthreads();
#pragma unroll
  for (int i = 0; i < 4; ++i)
    WT[(size_t)(n0 + ty + 8 * i) * Cz + k0 + tx] = f2bf(tile[tx][ty + 8 * i]);
}

// ---------------- qkv GEMM: 256x256 tile, BK=64, 8 waves, 4-phase/K-tile ----------------
// Regions: h0=A rows0-127, h1=B rows0-127, h2=B rows128-255, h3=A rows128-255.
// Per K-tile: ph0 reads A0(8)+B0(4) -> 16 MFMA A0xB0; ph1 reads B1(4) -> A0xB1;
// ph2 reads A1(8) -> A1xB0 (B0 from regs); ph3 reads NOTHING -> A1xB1 (regs).
// 24 ds_read_b128 / K-tile / wave (LDS time ~= MFMA time).
//
// STAGING LEDGER (stage-all burst at ph0; issue order h0,h1,h2,h3; in-order
// vmcnt retirement, 2 loads/half-tile):
//   entering kt.ph0 queue = [T.h2, T.h3] (T = tile kt; h0,h1 already retired)
//   ph0: +stage_all(T+1) -> 12 outstanding; end vmcnt(10) retires T.h2 (ph1)
//   ph1: end vmcnt(8) retires T.h3 (needed ph2)
//   ph2: no wait
//   ph3: end vmcnt(4) retires T1.h0,T1.h1 (needed next ph0)
//   -> every load has >= 4 phases issue-to-forced-complete (covers HBM lat).
//   Tail tile (no staging): vmcnt(2) @ph0, vmcnt(0) @ph1.
//   Race check: stage_all(T+1) writes buf 1-cb; its last readers ran at tile
//   kt-1 (h3 read at kt-1.ph2) -> >=4 barriers before the staging issue.
// Epilogue: bias; q cols pre-scaled; V cols stored transposed to vT[d][s].
__global__ __launch_bounds__(512, 2) void gemm_qkv(const u16* __restrict__ A,
                                                   const u16* __restrict__ BT,
                                                   const float* __restrict__ bias,
                                                   u16* __restrict__ Cout,
                                                   u16* __restrict__ vTout) {
  constexpr int K = Cz;        // 1024
  constexpr int N = 3 * Cz;    // 3072
  constexpr int KT = K / 64;   // 16 K-tiles
  __shared__ __align__(16) u16 L[2][4][128 * 64];  // 128 KiB

  const int t = threadIdx.x;
  const int wave = t >> 6, lane = t & 63;
  const int lm = lane & 15, lg = lane >> 4;
  const int wm = wave >> 2, wn = wave & 3;  // 2M x 4N wave grid

  // XCD-affine swizzle: linear bid -> each XCD gets 24 consecutive slots =
  // 2 full grid rows (A-panels L2-resident). 192 % 8 == 0 -> bijective.
  const int bid = blockIdx.y * 12 + blockIdx.x;
  const int swz = (bid & 7) * 24 + (bid >> 3);
  const int m0 = (swz / 12) * 256, n0 = (swz % 12) * 256;

  // gl_lds: LDS base wave-uniform (m104); lane i -> row 8w+(i>>3), seg i&7;
  // global side carries XOR swizzle: LDS[row][seg s] = global[row][s^(row&7)].
  const int srow = 8 * wave + (lane >> 3);
  const int sgl = ((lane & 7) ^ (lane >> 3)) * 8;
  const u16* aS = A + (size_t)(m0 + srow) * K + sgl;
  const u16* bS = BT + (size_t)(n0 + srow) * K + sgl;

  auto stage_all = [&](int kt) {  // issue order h0,h1,h2,h3 (ledger depends!)
    const int b = kt & 1;
    const size_t ko = (size_t)kt * 64;
    u16* d0 = &L[b][0][(8 * wave) * 64];
    gl_lds16(aS + ko, d0);
    gl_lds16(aS + ko + (size_t)64 * K, d0 + 64 * 64);
    u16* d1 = &L[b][1][(8 * wave) * 64];
    gl_lds16(bS + ko, d1);
    gl_lds16(bS + ko + (size_t)64 * K, d1 + 64 * 64);
    u16* d2 = &L[b][2][(8 * wave) * 64];
    gl_lds16(bS + ko + (size_t)128 * K, d2);
    gl_lds16(bS + ko + (size_t)192 * K, d2 + 64 * 64);
    u16* d3 = &L[b][3][(8 * wave) * 64];
    gl_lds16(aS + ko + (size_t)128 * K, d3);
    gl_lds16(aS + ko + (size_t)192 * K, d3 + 64 * 64);
  };

  f32x4 acc[2][2][4][2];
#pragma unroll
  for (int qa = 0; qa < 2; ++qa)
#pragma unroll
    for (int qb = 0; qb < 2; ++qb)
#pragma unroll
      for (int mt = 0; mt < 4; ++mt)
#pragma unroll
        for (int nt = 0; nt < 2; ++nt)
#pragma unroll
          for (int i = 0; i < 4; ++i) acc[qa][qb][mt][nt][i] = 0.f;

  const int roff0 = (lg ^ (lm & 7)) << 3;          // k-half 0 un-swizzle
  const int roff1 = ((lg + 4) ^ (lm & 7)) << 3;    // k-half 1
  const int arow = (64 * wm + lm) * 64;            // + 16*mt*64
  const int brow = (32 * wn + lm) * 64;            // + 16*nt*64

  // prologue: stage tile0; h0,h1 resident.
  stage_all(0);
  asm volatile("s_waitcnt vmcnt(4)" ::: "memory");
  __builtin_amdgcn_s_barrier();

  for (int kt = 0; kt < KT - 1; ++kt) {
    const int cb = kt & 1;
    const u16* Lc = &L[cb][0][0];
    bf16x8 af[4][2], bfr[2][2][2];  // bfr[qb][nt][h] held across phases
    // ---- ph0: read A0 + B0; stage-all tile kt+1 ----
#pragma unroll
    for (int mt = 0; mt < 4; ++mt) {
      af[mt][0] = *(const bf16x8*)&Lc[0 * 8192 + arow + 16 * mt * 64 + roff0];
      af[mt][1] = *(const bf16x8*)&Lc[0 * 8192 + arow + 16 * mt * 64 + roff1];
    }
#pragma unroll
    for (int nt = 0; nt < 2; ++nt) {
      bfr[0][nt][0] = *(const bf16x8*)&Lc[1 * 8192 + brow + 16 * nt * 64 + roff0];
      bfr[0][nt][1] = *(const bf16x8*)&Lc[1 * 8192 + brow + 16 * nt * 64 + roff1];
    }
    stage_all(kt + 1);
    __builtin_amdgcn_s_barrier();
    asm volatile("s_waitcnt lgkmcnt(0)" ::: "memory");
    __builtin_amdgcn_s_setprio(1);
#pragma unroll
    for (int mt = 0; mt < 4; ++mt)
#pragma unroll
      for (int nt = 0; nt < 2; ++nt) {
        acc[0][0][mt][nt] = MFMA32(af[mt][0], bfr[0][nt][0], acc[0][0][mt][nt]);
        acc[0][0][mt][nt] = MFMA32(af[mt][1], bfr[0][nt][1], acc[0][0][mt][nt]);
      }
    __builtin_amdgcn_s_setprio(0);
    asm volatile("s_waitcnt vmcnt(10)" ::: "memory");
    __builtin_amdgcn_s_barrier();
    // ---- ph1: read B1 ----
#pragma unroll
    for (int nt = 0; nt < 2; ++nt) {
      bfr[1][nt][0] = *(const bf16x8*)&Lc[2 * 8192 + brow + 16 * nt * 64 + roff0];
      bfr[1][nt][1] = *(const bf16x8*)&Lc[2 * 8192 + brow + 16 * nt * 64 + roff1];
    }
    __builtin_amdgcn_s_barrier();
    asm volatile("s_waitcnt lgkmcnt(0)" ::: "memory");
    __builtin_amdgcn_s_setprio(1);
#pragma unroll
    for (int mt = 0; mt < 4; ++mt)
#pragma unroll
      for (int nt = 0; nt < 2; ++nt) {
        acc[0][1][mt][nt] = MFMA32(af[mt][0], bfr[1][nt][0], acc[0][1][mt][nt]);
        acc[0][1][mt][nt] = MFMA32(af[mt][1], bfr[1][nt][1], acc[0][1][mt][nt]);
      }
    __builtin_amdgcn_s_setprio(0);
    asm volatile("s_waitcnt vmcnt(8)" ::: "memory");
    __builtin_amdgcn_s_barrier();
    // ---- ph2: read A1 (overwrites af); B0 from regs ----
#pragma unroll
    for (int mt = 0; mt < 4; ++mt) {
      af[mt][0] = *(const bf16x8*)&Lc[3 * 8192 + arow + 16 * mt * 64 + roff0];
      af[mt][1] = *(const bf16x8*)&Lc[3 * 8192 + arow + 16 * mt * 64 + roff1];
    }
    __builtin_amdgcn_s_barrier();
    asm volatile("s_waitcnt lgkmcnt(0)" ::: "memory");
    __builtin_amdgcn_s_setprio(1);
#pragma unroll
    for (int mt = 0; mt < 4; ++mt)
#pragma unroll
      for (int nt = 0; nt < 2; ++nt) {
        acc[1][0][mt][nt] = MFMA32(af[mt][0], bfr[0][nt][0], acc[1][0][mt][nt]);
        acc[1][0][mt][nt] = MFMA32(af[mt][1], bfr[0][nt][1], acc[1][0][mt][nt]);
      }
    __builtin_amdgcn_s_setprio(0);
    __builtin_amdgcn_s_barrier();
    // ---- ph3: registers only (A1 x B1) ----
    __builtin_amdgcn_s_setprio(1);
#pragma unroll
    for (int mt = 0; mt < 4; ++mt)
#pragma unroll
      for (int nt = 0; nt < 2; ++nt) {
        acc[1][1][mt][nt] = MFMA32(af[mt][0], bfr[1][nt][0], acc[1][1][mt][nt]);
        acc[1][1][mt][nt] = MFMA32(af[mt][1], bfr[1][nt][1], acc[1][1][mt][nt]);
      }
    __builtin_amdgcn_s_setprio(0);
    asm volatile("s_waitcnt vmcnt(4)" ::: "memory");
    __builtin_amdgcn_s_barrier();
  }

  {  // ---- tail tile kt = KT-1 (no staging; waits {2,0,-,-}) ----
    const int cb = (KT - 1) & 1;
    const u16* Lc = &L[cb][0][0];
    bf16x8 af[4][2], bfr[2][2][2];
#pragma unroll
    for (int mt = 0; mt < 4; ++mt) {
      af[mt][0] = *(const bf16x8*)&Lc[0 * 8192 + arow + 16 * mt * 64 + roff0];
      af[mt][1] = *(const bf16x8*)&Lc[0 * 8192 + arow + 16 * mt * 64 + roff1];
    }
#pragma unroll
    for (int nt = 0; nt < 2; ++nt) {
      bfr[0][nt][0] = *(const bf16x8*)&Lc[1 * 8192 + brow + 16 * nt * 64 + roff0];
      bfr[0][nt][1] = *(const bf16x8*)&Lc[1 * 8192 + brow + 16 * nt * 64 + roff1];
    }
    __builtin_amdgcn_s_barrier();
    asm volatile("s_waitcnt lgkmcnt(0)" ::: "memory");
#pragma unroll
    for (int mt = 0; mt < 4; ++mt)
#pragma unroll
      for (int nt = 0; nt < 2; ++nt) {
        acc[0][0][mt][nt] = MFMA32(af[mt][0], bfr[0][nt][0], acc[0][0][mt][nt]);
        acc[0][0][mt][nt] = MFMA32(af[mt][1], bfr[0][nt][1], acc[0][0][mt][nt]);
      }
    asm volatile("s_waitcnt vmcnt(2)" ::: "memory");
    __builtin_amdgcn_s_barrier();
#pragma unroll
    for (int nt = 0; nt < 2; ++nt) {
      bfr[1][nt][0] = *(const bf16x8*)&Lc[2 * 8192 + brow + 16 * nt * 64 + roff0];
      bfr[1][nt][1] = *(const bf16x8*)&Lc[2 * 8192 + brow + 16 * nt * 64 + roff1];
    }
    __builtin_amdgcn_s_barrier();
    asm volatile("s_waitcnt lgkmcnt(0)" ::: "memory");
#pragma unroll
    for (int mt = 0; mt < 4; ++mt)
#pragma unroll
      for (int nt = 0; nt < 2; ++nt) {
        acc[0][1][mt][nt] = MFMA32(af[mt][0], bfr[1][nt][0], acc[0][1][mt][nt]);
        acc[0][1][mt][nt] = MFMA32(af[mt][1], bfr[1][nt][1], acc[0][1][mt][nt]);
      }
    asm volatile("s_waitcnt vmcnt(0)" ::: "memory");
    __builtin_amdgcn_s_barrier();
#pragma unroll
    for (int mt = 0; mt < 4; ++mt) {
      af[mt][0] = *(const bf16x8*)&Lc[3 * 8192 + arow + 16 * mt * 64 + roff0];
      af[mt][1] = *(const bf16x8*)&Lc[3 * 8192 + arow + 16 * mt * 64 + roff1];
    }
    asm volatile("s_waitcnt lgkmcnt(0)" ::: "memory");
#pragma unroll
    for (int mt = 0; mt < 4; ++mt)
#pragma unroll
      for (int nt = 0; nt < 2; ++nt) {
        acc[1][0][mt][nt] = MFMA32(af[mt][0], bfr[0][nt][0], acc[1][0][mt][nt]);
        acc[1][0][mt][nt] = MFMA32(af[mt][1], bfr[0][nt][1], acc[1][0][mt][nt]);
        acc[1][1][mt][nt] = MFMA32(af[mt][0], bfr[1][nt][0], acc[1][1][mt][nt]);
        acc[1][1][mt][nt] = MFMA32(af[mt][1], bfr[1][nt][1], acc[1][1][mt][nt]);
      }
  }

  // epilogue: bias + q-scale; V cols -> transposed vT store
#pragma unroll
  for (int qa = 0; qa < 2; ++qa)
#pragma unroll
    for (int qb = 0; qb < 2; ++qb)
#pragma unroll
      for (int nt = 0; nt < 2; ++nt) {
        const int gc = n0 + 128 * qb + 32 * wn + 16 * nt + lm;
        const float bv = bias[gc];
        if (gc >= 2 * Cz) {  // V column (block-uniform branch)
          const int dg = gc - 2 * Cz;
#pragma unroll
          for (int mt = 0; mt < 4; ++mt) {
            const int gr0 = m0 + 128 * qa + 64 * wm + 16 * mt + 4 * lg;
            const int bb = gr0 >> 11, s0 = gr0 & 2047;
            const f32x4 av = acc[qa][qb][mt][nt];
            ushort4 o = {f2bf(av[0] + bv), f2bf(av[1] + bv),
                         f2bf(av[2] + bv), f2bf(av[3] + bv)};
            *(ushort4*)(vTout + (((size_t)(bb * 1024 + dg)) << 11) + s0) = o;
          }
        } else {
          const float sc = (gc < Cz) ? QSCALE : 1.f;
#pragma unroll
          for (int mt = 0; mt < 4; ++mt)
#pragma unroll
            for (int i = 0; i < 4; ++i) {
              const int gr = m0 + 128 * qa + 64 * wm + 16 * mt + 4 * lg + i;
              Cout[(size_t)gr * N + gc] = f2bf((acc[qa][qb][mt][nt][i] + bv) * sc);
            }
        }
      }
}

// ---------- C[M][N] = A[M][K]*BT[N][K]^T + bias; 128xTN tile, BK=64 ----------
// (kept for the proj GEMM: N=1024 would underfill the 256^2 template's grid)
template <bool OUT_BF16, int TN, bool VSPLIT>
__global__ __launch_bounds__(256) void gemm_bt(const u16* __restrict__ A,
                                               const u16* __restrict__ BT,
                                               const float* __restrict__ bias,
                                               void* __restrict__ Cout,
                                               u16* __restrict__ vTout,
                                               int M, int N, int K,
                                               int qcols, float qscale) {
  __shared__ __align__(16) u16 As[128 * 64];
  __shared__ __align__(16) u16 Bs[TN * 64];
  constexpr int NT = TN / 32;
  const int t = threadIdx.x;
  const int wave = t >> 6, lane = t & 63;
  const int lm = lane & 15, lg = lane >> 4;
  const int wm = wave >> 1, wn = wave & 1;
  const int m0 = blockIdx.y * 128, n0 = blockIdx.x * TN;

  const int lrow = lane >> 3;                 // 0..7
  const int gseg = (lane & 7) ^ lrow;         // global col-seg (XOR swizzle)
  const size_t a_base = (size_t)(m0 + 32 * wave + lrow) * K + gseg * 8;
  u16* const a_lds = &As[(32 * wave) * 64];
  const size_t b_base = (size_t)(n0 + (TN / 4) * wave + lrow) * K + gseg * 8;
  u16* const b_lds = &Bs[((TN / 4) * wave) * 64];

  f32x4 acc[4][NT];
#pragma unroll
  for (int mt = 0; mt < 4; ++mt)
#pragma unroll
    for (int nt = 0; nt < NT; ++nt)
#pragma unroll
      for (int i = 0; i < 4; ++i) acc[mt][nt][i] = 0.f;

  for (int k0 = 0; k0 < K; k0 += 64) {
    __syncthreads();
#pragma unroll
    for (int i = 0; i < 4; ++i)
      gl_lds16(A + a_base + (size_t)(8 * i) * K + k0, a_lds + i * 8 * 64);
#pragma unroll
    for (int i = 0; i < NT; ++i)
      gl_lds16(BT + b_base + (size_t)(8 * i) * K + k0, b_lds + i * 8 * 64);
    __syncthreads();

#pragma unroll
    for (int h = 0; h < 2; ++h) {
      const int rs = ((lg + 4 * h) ^ (lm & 7)) * 8;
      bf16x8 af[4], bfr[NT];
#pragma unroll
      for (int mt = 0; mt < 4; ++mt)
        af[mt] = *(const bf16x8*)&As[(64 * wm + 16 * mt + lm) * 64 + rs];
#pragma unroll
      for (int nt = 0; nt < NT; ++nt)
        bfr[nt] = *(const bf16x8*)&Bs[((TN / 2) * wn + 16 * nt + lm) * 64 + rs];
#pragma unroll
      for (int mt = 0; mt < 4; ++mt)
#pragma unroll
        for (int nt = 0; nt < NT; ++nt)
          acc[mt][nt] = MFMA32(af[mt], bfr[nt], acc[mt][nt]);
    }
  }

#pragma unroll
  for (int nt = 0; nt < NT; ++nt) {
    int gc = n0 + (TN / 2) * wn + 16 * nt + lm;
    float bv = bias[gc];
    if (VSPLIT && gc >= 2 * Cz) {
      // V column -> transposed store: vTout[(b*1024 + dg)][s0..s0+3]
      const int dg = gc - 2 * Cz;
#pragma unroll
      for (int mt = 0; mt < 4; ++mt) {
        const int gr0 = m0 + 64 * wm + 16 * mt + 4 * lg;
        const int bb = gr0 >> 11, s0 = gr0 & 2047;
        ushort4 o = {f2bf(acc[mt][nt][0] + bv), f2bf(acc[mt][nt][1] + bv),
                     f2bf(acc[mt][nt][2] + bv), f2bf(acc[mt][nt][3] + bv)};
        *(ushort4*)(vTout + (((size_t)(bb * 1024 + dg)) << 11) + s0) = o;
      }
      continue;
    }
    float sc = (gc < qcols) ? qscale : 1.f;
#pragma unroll
    for (int mt = 0; mt < 4; ++mt) {
#pragma unroll
      for (int i = 0; i < 4; ++i) {
        int gr = m0 + 64 * wm + 16 * mt + 4 * lg + i;
        float v = (acc[mt][nt][i] + bv) * sc;
        if (OUT_BF16)
          ((u16*)Cout)[(size_t)gr * N + gc] = f2bf(v);
        else
          ((float*)Cout)[(size_t)gr * N + gc] = v;
      }
    }
  }
}

// ---------------- flash attention, MFMA bf16, m=0 softmax, S^T ----------------
// 1D grid 1024: x = qtp*32+bh (XCD-affine); balanced qt = qtp<16?qtp:47-qtp.
// Wave w owns Q-rows [64qt+16w,+16). S^T = K*Q^T; p = exp2(S^T) packed
// in-register as 16x16x16-MFMA A-frag (P never touches LDS). K and V staged
// with global_load_lds (w=16) into unpadded stride-64 LDS; conflicts killed
// by XOR swizzle on the GLOBAL address (seg_g = seg_l ^ (row&7)) -- legal
// since gl_lds global addrs are per-lane, LDS base wave-uniform (m104).
// Frag reads un-swizzle; K b128 and V b64 patterns are bank-minimal (free).
// Double-buffered, ONE barrier/stage; gl_lds for kt+1 issued right after the
// barrier. V comes from pre-transposed vT[d][s] (written by qkv GEMM).
__global__ __launch_bounds__(256) void attn_kernel(const u16* __restrict__ qkv,
                                                   const u16* __restrict__ vT,
                                                   u16* __restrict__ yb) {
  __shared__ __align__(16) u16 KsL[2][64 * 64];
  __shared__ __align__(16) u16 VtL[2][64 * 64];

  const int t = threadIdx.x;
  const int wave = t >> 6, lane = t & 63;
  const int lm = lane & 15, lg = lane >> 4;
  const int x = blockIdx.x;
  const int bh = x & 31, qtp = x >> 5;
  const int qt = (qtp < 16) ? qtp : 47 - qtp;  // CU-balanced map
  const int b = bh >> 4, h = bh & 15;
  const int q0 = qt * 64;
  const size_t rowstride = 3 * Cz;
  const u16* qbase = qkv + (size_t)b * Tz * rowstride + h * Dz;
  const u16* vTbh = vT + ((size_t)(b * Hz + h) * Dz) * Tz;  // [64][2048]

  // Q fragments: B-operand of the S^T MFMA (lane lm = q-col, elems = d)
  bf16x8 qf[2];
  {
    const u16* qrow = qbase + (size_t)(q0 + wave * 16 + lm) * rowstride + (lg << 3);
    qf[0] = *(const bf16x8*)qrow;
    qf[1] = *(const bf16x8*)(qrow + 32);
  }

  float psum = 0.f;  // l for q = 16*wave + lm (partial over this lane's s)
  f32x4 Oa[4];       // Oa[dt][r] = O[q=16w+4lg+r][d=16dt+lm]
#pragma unroll
  for (int i = 0; i < 4; ++i)
#pragma unroll
    for (int j = 0; j < 4; ++j) Oa[i][j] = 0.f;

  // staging: wave w stages rows [16w,16w+16) of both K and V tiles.
  // lane i -> row +(i>>3), LDS seg i&7 holding GLOBAL seg (i&7)^(i>>3).
  const int srow = lane >> 3;              // 0..7
  const int sgl = ((lane & 7) ^ srow) * 8; // global col offset (swizzled)
  const u16* kstg = qbase + Cz + (size_t)(16 * wave + srow) * rowstride + sgl;
  const u16* vstg = vTbh + (size_t)(16 * wave + srow) * Tz + sgl;

  auto stage_issue = [&](int kt, int buf) {
#pragma unroll
    for (int c2 = 0; c2 < 2; ++c2) {
      gl_lds16(kstg + (size_t)(8 * c2) * rowstride + (size_t)(64 * kt) * rowstride,
               &KsL[buf][(16 * wave + 8 * c2) * 64]);
      gl_lds16(vstg + (size_t)(8 * c2) * Tz + 64 * kt,
               &VtL[buf][(16 * wave + 8 * c2) * 64]);
    }
  };

  stage_issue(0, 0);  // prologue; first barrier drains it

  for (int kt = 0; kt <= qt; ++kt) {
    __syncthreads();  // buf(kt&1) loads drained; prior readers of other buf done
    const int cb = kt & 1;
    if (kt + 1 <= qt) stage_issue(kt + 1, 1 - cb);

    // ---- S^T = K Q^T (pre-scaled): lane gets s=16c+4lg+r, q=16w+lm ----
    f32x4 S[4];
#pragma unroll
    for (int c = 0; c < 4; ++c) {
      const int rb = (16 * c + lm) * 64;
      bf16x8 k0 = *(const bf16x8*)&KsL[cb][rb + ((lg ^ (lm & 7)) << 3)];
      bf16x8 k1 = *(const bf16x8*)&KsL[cb][rb + (((lg + 4) ^ (lm & 7)) << 3)];
      f32x4 s;
#pragma unroll
      for (int i = 0; i < 4; ++i) s[i] = 0.f;
      s = MFMA32(k0, qf[0], s);
      s = MFMA32(k1, qf[1], s);
      S[c] = s;
    }

    // ---- p = exp2(S^T), diag mask, accumulate l, pack A-frags in-reg ----
    const bool diag = (kt == qt);
    const int qloc = 16 * wave + lm;
    bf16x4 pf[4];
#pragma unroll
    for (int c = 0; c < 4; ++c) {
#pragma unroll
      for (int r = 0; r < 4; ++r) {
        float p = fexp2(S[c][r]);
        if (diag && (c * 16 + 4 * lg + r) > qloc) p = 0.f;
        psum += p;
        pf[c][r] = (short)f2bf(p);
      }
    }

    // ---- O += P V: K=16 MFMAs, A=pf (registers), B from VtL[d][s] ----
#pragma unroll
    for (int dt = 0; dt < 4; ++dt) {
      const int rb = (16 * dt + lm) * 64;
#pragma unroll
      for (int c = 0; c < 4; ++c) {
        const int off = (((2 * c + (lg >> 1)) ^ (lm & 7)) << 3) + 4 * (lg & 1);
        bf16x4 vfr = *(const bf16x4*)&VtL[cb][rb + off];
        Oa[dt] = mfma16(pf[c], vfr, Oa[dt]);
      }
    }
  }

  // ---- epilogue: l-reduce over lg, redistribute inv, bounce via KsL[0] ----
  float s = psum;
  s += __shfl_xor(s, 16);
  s += __shfl_xor(s, 32);
  const float linv = 1.f / s;  // l(q=16w+lm), valid at all lg
  float invq[4];
#pragma unroll
  for (int r = 0; r < 4; ++r)
    invq[r] = __shfl(linv, 20 * lg + r);  // lane with lm = 4lg+r (same lg)
  __syncthreads();  // all KsL/VtL readers done; reuse KsL[0] as store bounce
#pragma unroll
  for (int dt = 0; dt < 4; ++dt)
#pragma unroll
    for (int r = 0; r < 4; ++r)
      KsL[0][(16 * wave + 4 * lg + r) * 64 + 16 * dt + lm] =
          f2bf(Oa[dt][r] * invq[r]);
  __syncthreads();
  {
    const int row = lane >> 2, seg = lane & 3;
    const uint4* src = (const uint4*)&KsL[0][(16 * wave + row) * 64 + seg * 16];
    uint4 v0 = src[0];
    uint4 v1 = src[1];
    u16* dst = yb + (size_t)(b * Tz + q0 + 16 * wave + row) * Cz + h * Dz + seg * 16;
    *(uint4*)dst = v0;
    *(uint4*)(dst + 8) = v1;
  }
}

extern "C" void kernel_launch(void* const* d_in, const int* in_sizes, int n_in,
                              void* d_out, int out_size, void* d_ws, size_t ws_size,
                              hipStream_t stream) {
  const float* x      = (const float*)d_in[0];
  const float* w_attn = (const float*)d_in[1];
  const float* b_attn = (const float*)d_in[2];
  const float* w_proj = (const float*)d_in[3];
  const float* b_proj = (const float*)d_in[4];

  char* ws = (char*)d_ws;
  u16* xb   = (u16*)(ws);                        //  8 MB: x bf16 [4096,1024]
  u16* waT  = (u16*)(ws + (8ull << 20));         //  6 MB: w_attn^T bf16 [3072,1024]
  u16* wpT  = (u16*)(ws + (14ull << 20));        //  2 MB: w_proj^T bf16 [1024,1024]
  u16* qkvb = (u16*)(ws + (16ull << 20));        // 24 MB: qkv bf16 (q pre-scaled; V cols unused)
  u16* yb   = (u16*)(ws + (40ull << 20));        //  8 MB: y bf16 [4096,1024]
  u16* vTt  = (u16*)(ws + (48ull << 20));        //  8 MB: V^T bf16 [2*16*64][2048]

  const int M = Bz * Tz;  // 4096

  prep_kernel<<<NCAST + NTA + 1024, 256, 0, stream>>>(x, w_attn, w_proj, xb, waT, wpT);
  gemm_qkv<<<dim3(12, 16), 512, 0, stream>>>(xb, waT, b_attn, qkvb, vTt);
  attn_kernel<<<1024, 256, 0, stream>>>(qkvb, vTt, yb);
  gemm_bt<false, 64, false><<<dim3(Cz / 64, M / 128), 256, 0, stream>>>(
      yb, wpT, b_proj, d_out, nullptr, M, Cz, Cz, 0, 1.f);
}

// Round 4
// 171.891 us; speedup vs baseline: 1.0334x; 1.0261x over previous
//
#include <hip/hip_runtime.h>

// Causal self-attention fwd: B=2,T=2048,C=1024,H=16,D=64, scale=0.1/sqrt(D)
// prep (cast x + transpose weights); qkv GEMM = 256x256 m201-faithful 8-phase
// pair schedule: 2-K-tile unroll, 1 half-tile staged per phase (>=6-phase
// issue-to-read distance), uniform non-draining vmcnt(10), lgkmcnt(8)
// throttle, setprio around MFMA clusters, XCD-affine grid, global-side XOR
// swizzle. flash attn + proj GEMM unchanged (proven).

#define Bz 2
#define Tz 2048
#define Cz 1024
#define Hz 16
#define Dz 64
// SCALE * log2(e): q pre-scaled so attn does p = exp2(S) directly
#define QSCALE 0.01803368801111437f

typedef unsigned short u16;
typedef short bf16x4 __attribute__((ext_vector_type(4)));
typedef short bf16x8 __attribute__((ext_vector_type(8)));
typedef float f32x4 __attribute__((ext_vector_type(4)));

#define MFMA32(A, B, C) __builtin_amdgcn_mfma_f32_16x16x32_bf16(A, B, C, 0, 0, 0)

// K=16 bf16 MFMA. Guard with __HIP_DEVICE_COMPILE__ (R8 lesson: __has_builtin
// is unreliable for aux-target builtins in the host pass).
__device__ inline f32x4 mfma16(bf16x4 a, bf16x4 b, f32x4 c) {
#if defined(__HIP_DEVICE_COMPILE__)
  return __builtin_amdgcn_mfma_f32_16x16x16bf16_1k(a, b, c, 0, 0, 0);
#else
  return c;  // host pass placeholder, never executed
#endif
}

__device__ inline u16 f2bf(float f) {  // round-half-up: 2 VALU, <=0.5 ulp
  return (u16)((__float_as_uint(f) + 0x8000u) >> 16);
}

__device__ inline float fexp2(float x) {  // raw v_exp_f32 (R6-proven guard)
#if __has_builtin(__builtin_amdgcn_exp2f)
  return __builtin_amdgcn_exp2f(x);
#else
  return exp2f(x);
#endif
}

__device__ inline void gl_lds16(const u16* g, u16* l) {
  __builtin_amdgcn_global_load_lds(
      (const __attribute__((address_space(1))) void*)g,
      (__attribute__((address_space(3))) void*)l, 16, 0, 0);
}

// ------------- prep: cast x->bf16 + transpose/cast both weights -------------
#define NCAST 4096   // (4096*1024/4)/256
#define NTA   3072   // (3072/32)*(1024/32)
__global__ __launch_bounds__(256) void prep_kernel(const float* __restrict__ x,
                                                   const float* __restrict__ wa,
                                                   const float* __restrict__ wp,
                                                   u16* __restrict__ xb,
                                                   u16* __restrict__ waT,
                                                   u16* __restrict__ wpT) {
  const int bx = blockIdx.x, t = threadIdx.x;
  if (bx < NCAST) {
    int i = bx * 256 + t;
    float4 v = ((const float4*)x)[i];
    ushort4 o = {f2bf(v.x), f2bf(v.y), f2bf(v.z), f2bf(v.w)};
    ((ushort4*)xb)[i] = o;
    return;
  }
  __shared__ float tile[32][33];
  const float* W;
  u16* WT;
  int N, idx;
  if (bx < NCAST + NTA) {
    W = wa; WT = waT; N = 3 * Cz; idx = bx - NCAST;
  } else {
    W = wp; WT = wpT; N = Cz; idx = bx - NCAST - NTA;
  }
  const int n0 = (idx % (N / 32)) * 32, k0 = (idx / (N / 32)) * 32;
  const int tx = t & 31, ty = t >> 5;  // (32, 8)
#pragma unroll
  for (int i = 0; i < 4; ++i)
    tile[ty + 8 * i][tx] = W[(size_t)(k0 + ty + 8 * i) * N + n0 + tx];
  __syncthreads();
#pragma unroll
  for (int i = 0; i < 4; ++i)
    WT[(size_t)(n0 + ty + 8 * i) * Cz + k0 + tx] = f2bf(tile[tx][ty + 8 * i]);
}

// -------- qkv GEMM: 256x256, BK=64, 8 waves, 8-phase 2-K-tile pair loop --------
// Regions per buffer: 0=A0 (A rows 0-127), 1=B0, 2=B1, 3=A1.
// Pair (t0=2i buf0, t1=2i+1 buf1); per tile 4 quadrant-phases, order
// (00,01,11,10), reads {A0+B0=12, B1=4, A1=8, 0} (B held in regs).
// STAGING: exactly 1 half-tile (2 gl_lds) per phase:
//   ph0: t1.A1 | ph1: t2.A0 | ph2: t2.B0 | ph3: t2.B1
//   ph4: t2.A1 | ph5: t3.A0 | ph6: t3.B0 | ph7: t3.B1   (t2=2i+2, t3=2i+3)
// Region-free proof: each stage overwrites a region whose last ds_read is
// >=1 barrier-pair earlier (readers pass lgkmcnt(0) before their 2nd
// barrier).  Deadline: every stage issued >=6 phases before its first read.
// vmcnt(10) at every phase end = allow 5 stages in flight -> stage(p-5)
// complete, exactly the 6-phase deadline.  Prologue stages 7 half-tiles
// (t0 all + t1.{A0,B0,B1}), vmcnt(10).  Tail pair: ph0 stages t15.A1 only;
// ladder vmcnt {8,8,-,4,2,0}.
__global__ __launch_bounds__(512, 2) void gemm_qkv(const u16* __restrict__ A,
                                                   const u16* __restrict__ BT,
                                                   const float* __restrict__ bias,
                                                   u16* __restrict__ Cout,
                                                   u16* __restrict__ vTout) {
  constexpr int K = Cz;        // 1024
  constexpr int N = 3 * Cz;    // 3072
  constexpr int KT = K / 64;   // 16 K-tiles (8 pairs)
  __shared__ __align__(16) u16 L[2][4][128 * 64];  // 128 KiB

  const int t = threadIdx.x;
  const int wave = t >> 6, lane = t & 63;
  const int lm = lane & 15, lg = lane >> 4;
  const int wm = wave >> 2, wn = wave & 3;  // 2M x 4N wave grid

  // XCD-affine swizzle (192 % 8 == 0 -> bijective; 2 grid rows per XCD)
  const int bid = blockIdx.y * 12 + blockIdx.x;
  const int swz = (bid & 7) * 24 + (bid >> 3);
  const int m0 = (swz / 12) * 256, n0 = (swz % 12) * 256;

  // gl_lds: LDS base wave-uniform (m104); lane i -> row 8w+(i>>3), seg i&7;
  // global addr carries XOR swizzle: LDS[row][seg s] = global[row][s^(row&7)].
  const int srow = 8 * wave + (lane >> 3);
  const int sgl = ((lane & 7) ^ (lane >> 3)) * 8;

  auto stage = [&](int kt, int rg) {  // one half-tile = 2 gl_lds
    const u16* src = (rg == 0 || rg == 3)
        ? A + (size_t)(m0 + ((rg == 3) ? 128 : 0) + srow) * K
        : BT + (size_t)(n0 + ((rg == 2) ? 128 : 0) + srow) * K;
    src += (size_t)kt * 64 + sgl;
    u16* dst = &L[kt & 1][rg][(8 * wave) * 64];
    gl_lds16(src, dst);
    gl_lds16(src + (size_t)64 * K, dst + 64 * 64);
  };

  f32x4 acc[2][2][4][2];
#pragma unroll
  for (int qa = 0; qa < 2; ++qa)
#pragma unroll
    for (int qb = 0; qb < 2; ++qb)
#pragma unroll
      for (int mt = 0; mt < 4; ++mt)
#pragma unroll
        for (int nt = 0; nt < 2; ++nt)
#pragma unroll
          for (int i = 0; i < 4; ++i) acc[qa][qb][mt][nt][i] = 0.f;

  const int roff0 = (lg ^ (lm & 7)) << 3;        // k-half 0 un-swizzle
  const int roff1 = ((lg + 4) ^ (lm & 7)) << 3;  // k-half 1
  const int arow = (64 * wm + lm) * 64;          // + 1024*mt
  const int brow = (32 * wn + lm) * 64;          // + 1024*nt

  bf16x8 af[4][2], bfr[2][2][2];

#define RD_A(BUF, RG)                                                         \
  _Pragma("unroll") for (int mt = 0; mt < 4; ++mt) {                          \
    af[mt][0] = *(const bf16x8*)&L[BUF][RG][arow + 1024 * mt + roff0];        \
    af[mt][1] = *(const bf16x8*)&L[BUF][RG][arow + 1024 * mt + roff1];        \
  }
#define RD_B(BUF, RG, QB)                                                     \
  _Pragma("unroll") for (int nt = 0; nt < 2; ++nt) {                          \
    bfr[QB][nt][0] = *(const bf16x8*)&L[BUF][RG][brow + 1024 * nt + roff0];   \
    bfr[QB][nt][1] = *(const bf16x8*)&L[BUF][RG][brow + 1024 * nt + roff1];   \
  }
#define DO_MFMA(QA, QB)                                                       \
  __builtin_amdgcn_s_setprio(1);                                             \
  _Pragma("unroll") for (int mt = 0; mt < 4; ++mt)                            \
      _Pragma("unroll") for (int nt = 0; nt < 2; ++nt) {                      \
    acc[QA][QB][mt][nt] =                                                     \
        MFMA32(af[mt][0], bfr[QB][nt][0], acc[QA][QB][mt][nt]);               \
    acc[QA][QB][mt][nt] =                                                     \
        MFMA32(af[mt][1], bfr[QB][nt][1], acc[QA][QB][mt][nt]);               \
  }                                                                           \
  __builtin_amdgcn_s_setprio(0);
#define BAR __builtin_amdgcn_s_barrier()
#define WVM(NN) asm volatile("s_waitcnt vmcnt(" #NN ")" ::: "memory")
#define WLG(NN) asm volatile("s_waitcnt lgkmcnt(" #NN ")" ::: "memory")

  // prologue: t0 all 4 + t1.{A0,B0,B1} (7 stages, issue order = ledger order)
  stage(0, 0); stage(0, 1); stage(0, 2); stage(0, 3);
  stage(1, 0); stage(1, 1); stage(1, 2);
  WVM(10);  // 14 loads out, allow 10 -> t0.A0,t0.B0 resident
  BAR;

  for (int i = 0; i < KT / 2 - 1; ++i) {
    const int t1 = 2 * i + 1, t2 = 2 * i + 2, t3 = 2 * i + 3;
    // ---- ph0: tile t0 quadrant (0,0) ----
    RD_A(0, 0) RD_B(0, 1, 0) stage(t1, 3);
    WLG(8);
    BAR; WLG(0); DO_MFMA(0, 0) WVM(10); BAR;
    // ---- ph1: (0,1) ----
    RD_B(0, 2, 1) stage(t2, 0);
    BAR; WLG(0); DO_MFMA(0, 1) WVM(10); BAR;
    // ---- ph2: (1,1) ----
    RD_A(0, 3) stage(t2, 1);
    BAR; WLG(0); DO_MFMA(1, 1) WVM(10); BAR;
    // ---- ph3: (1,0) regs only ----
    stage(t2, 2);
    BAR; DO_MFMA(1, 0) WVM(10); BAR;
    // ---- ph4: tile t1 quadrant (0,0) ----
    RD_A(1, 0) RD_B(1, 1, 0) stage(t2, 3);
    WLG(8);
    BAR; WLG(0); DO_MFMA(0, 0) WVM(10); BAR;
    // ---- ph5: (0,1) ----
    RD_B(1, 2, 1) stage(t3, 0);
    BAR; WLG(0); DO_MFMA(0, 1) WVM(10); BAR;
    // ---- ph6: (1,1) ----
    RD_A(1, 3) stage(t3, 1);
    BAR; WLG(0); DO_MFMA(1, 1) WVM(10); BAR;
    // ---- ph7: (1,0) regs only ----
    stage(t3, 2);
    BAR; DO_MFMA(1, 0) WVM(10); BAR;
  }

  {  // ---- tail pair: tiles KT-2 (buf0), KT-1 (buf1); ladder drains ----
    RD_A(0, 0) RD_B(0, 1, 0) stage(KT - 1, 3);
    WLG(8);
    BAR; WLG(0); DO_MFMA(0, 0) WVM(8); BAR;
    RD_B(0, 2, 1)
    BAR; WLG(0); DO_MFMA(0, 1) WVM(8); BAR;
    RD_A(0, 3)
    BAR; WLG(0); DO_MFMA(1, 1) BAR;
    BAR; DO_MFMA(1, 0) WVM(4); BAR;
    RD_A(1, 0) RD_B(1, 1, 0)
    BAR; WLG(0); DO_MFMA(0, 0) WVM(2); BAR;
    RD_B(1, 2, 1)
    BAR; WLG(0); DO_MFMA(0, 1) WVM(0); BAR;
    RD_A(1, 3)
    BAR; WLG(0); DO_MFMA(1, 1)
    DO_MFMA(1, 0)
  }
#undef RD_A
#undef RD_B
#undef DO_MFMA
#undef BAR
#undef WVM
#undef WLG

  // epilogue: bias + q-scale; V cols -> transposed vT store
#pragma unroll
  for (int qa = 0; qa < 2; ++qa)
#pragma unroll
    for (int qb = 0; qb < 2; ++qb)
#pragma unroll
      for (int nt = 0; nt < 2; ++nt) {
        const int gc = n0 + 128 * qb + 32 * wn + 16 * nt + lm;
        const float bv = bias[gc];
        if (gc >= 2 * Cz) {  // V column (block-uniform branch)
          const int dg = gc - 2 * Cz;
#pragma unroll
          for (int mt = 0; mt < 4; ++mt) {
            const int gr0 = m0 + 128 * qa + 64 * wm + 16 * mt + 4 * lg;
            const int bb = gr0 >> 11, s0 = gr0 & 2047;
            const f32x4 av = acc[qa][qb][mt][nt];
            ushort4 o = {f2bf(av[0] + bv), f2bf(av[1] + bv),
                         f2bf(av[2] + bv), f2bf(av[3] + bv)};
            *(ushort4*)(vTout + (((size_t)(bb * 1024 + dg)) << 11) + s0) = o;
          }
        } else {
          const float sc = (gc < Cz) ? QSCALE : 1.f;
#pragma unroll
          for (int mt = 0; mt < 4; ++mt)
#pragma unroll
            for (int i = 0; i < 4; ++i) {
              const int gr = m0 + 128 * qa + 64 * wm + 16 * mt + 4 * lg + i;
              Cout[(size_t)gr * N + gc] = f2bf((acc[qa][qb][mt][nt][i] + bv) * sc);
            }
        }
      }
}

// ---------- C[M][N] = A[M][K]*BT[N][K]^T + bias; 128xTN tile, BK=64 ----------
// (kept for the proj GEMM)
template <bool OUT_BF16, int TN, bool VSPLIT>
__global__ __launch_bounds__(256) void gemm_bt(const u16* __restrict__ A,
                                               const u16* __restrict__ BT,
                                               const float* __restrict__ bias,
                                               void* __restrict__ Cout,
                                               u16* __restrict__ vTout,
                                               int M, int N, int K,
                                               int qcols, float qscale) {
  __shared__ __align__(16) u16 As[128 * 64];
  __shared__ __align__(16) u16 Bs[TN * 64];
  constexpr int NT = TN / 32;
  const int t = threadIdx.x;
  const int wave = t >> 6, lane = t & 63;
  const int lm = lane & 15, lg = lane >> 4;
  const int wm = wave >> 1, wn = wave & 1;
  const int m0 = blockIdx.y * 128, n0 = blockIdx.x * TN;

  const int lrow = lane >> 3;                 // 0..7
  const int gseg = (lane & 7) ^ lrow;         // global col-seg (XOR swizzle)
  const size_t a_base = (size_t)(m0 + 32 * wave + lrow) * K + gseg * 8;
  u16* const a_lds = &As[(32 * wave) * 64];
  const size_t b_base = (size_t)(n0 + (TN / 4) * wave + lrow) * K + gseg * 8;
  u16* const b_lds = &Bs[((TN / 4) * wave) * 64];

  f32x4 acc[4][NT];
#pragma unroll
  for (int mt = 0; mt < 4; ++mt)
#pragma unroll
    for (int nt = 0; nt < NT; ++nt)
#pragma unroll
      for (int i = 0; i < 4; ++i) acc[mt][nt][i] = 0.f;

  for (int k0 = 0; k0 < K; k0 += 64) {
    __syncthreads();
#pragma unroll
    for (int i = 0; i < 4; ++i)
      gl_lds16(A + a_base + (size_t)(8 * i) * K + k0, a_lds + i * 8 * 64);
#pragma unroll
    for (int i = 0; i < NT; ++i)
      gl_lds16(BT + b_base + (size_t)(8 * i) * K + k0, b_lds + i * 8 * 64);
    __syncthreads();

#pragma unroll
    for (int h = 0; h < 2; ++h) {
      const int rs = ((lg + 4 * h) ^ (lm & 7)) * 8;
      bf16x8 af[4], bfr[NT];
#pragma unroll
      for (int mt = 0; mt < 4; ++mt)
        af[mt] = *(const bf16x8*)&As[(64 * wm + 16 * mt + lm) * 64 + rs];
#pragma unroll
      for (int nt = 0; nt < NT; ++nt)
        bfr[nt] = *(const bf16x8*)&Bs[((TN / 2) * wn + 16 * nt + lm) * 64 + rs];
#pragma unroll
      for (int mt = 0; mt < 4; ++mt)
#pragma unroll
        for (int nt = 0; nt < NT; ++nt)
          acc[mt][nt] = MFMA32(af[mt], bfr[nt], acc[mt][nt]);
    }
  }

#pragma unroll
  for (int nt = 0; nt < NT; ++nt) {
    int gc = n0 + (TN / 2) * wn + 16 * nt + lm;
    float bv = bias[gc];
    if (VSPLIT && gc >= 2 * Cz) {
      const int dg = gc - 2 * Cz;
#pragma unroll
      for (int mt = 0; mt < 4; ++mt) {
        const int gr0 = m0 + 64 * wm + 16 * mt + 4 * lg;
        const int bb = gr0 >> 11, s0 = gr0 & 2047;
        ushort4 o = {f2bf(acc[mt][nt][0] + bv), f2bf(acc[mt][nt][1] + bv),
                     f2bf(acc[mt][nt][2] + bv), f2bf(acc[mt][nt][3] + bv)};
        *(ushort4*)(vTout + (((size_t)(bb * 1024 + dg)) << 11) + s0) = o;
      }
      continue;
    }
    float sc = (gc < qcols) ? qscale : 1.f;
#pragma unroll
    for (int mt = 0; mt < 4; ++mt) {
#pragma unroll
      for (int i = 0; i < 4; ++i) {
        int gr = m0 + 64 * wm + 16 * mt + 4 * lg + i;
        float v = (acc[mt][nt][i] + bv) * sc;
        if (OUT_BF16)
          ((u16*)Cout)[(size_t)gr * N + gc] = f2bf(v);
        else
          ((float*)Cout)[(size_t)gr * N + gc] = v;
      }
    }
  }
}

// ---------------- flash attention, MFMA bf16, m=0 softmax, S^T ----------------
__global__ __launch_bounds__(256) void attn_kernel(const u16* __restrict__ qkv,
                                                   const u16* __restrict__ vT,
                                                   u16* __restrict__ yb) {
  __shared__ __align__(16) u16 KsL[2][64 * 64];
  __shared__ __align__(16) u16 VtL[2][64 * 64];

  const int t = threadIdx.x;
  const int wave = t >> 6, lane = t & 63;
  const int lm = lane & 15, lg = lane >> 4;
  const int x = blockIdx.x;
  const int bh = x & 31, qtp = x >> 5;
  const int qt = (qtp < 16) ? qtp : 47 - qtp;  // CU-balanced map
  const int b = bh >> 4, h = bh & 15;
  const int q0 = qt * 64;
  const size_t rowstride = 3 * Cz;
  const u16* qbase = qkv + (size_t)b * Tz * rowstride + h * Dz;
  const u16* vTbh = vT + ((size_t)(b * Hz + h) * Dz) * Tz;  // [64][2048]

  bf16x8 qf[2];
  {
    const u16* qrow = qbase + (size_t)(q0 + wave * 16 + lm) * rowstride + (lg << 3);
    qf[0] = *(const bf16x8*)qrow;
    qf[1] = *(const bf16x8*)(qrow + 32);
  }

  float psum = 0.f;
  f32x4 Oa[4];
#pragma unroll
  for (int i = 0; i < 4; ++i)
#pragma unroll
    for (int j = 0; j < 4; ++j) Oa[i][j] = 0.f;

  const int srow = lane >> 3;              // 0..7
  const int sgl = ((lane & 7) ^ srow) * 8; // global col offset (swizzled)
  const u16* kstg = qbase + Cz + (size_t)(16 * wave + srow) * rowstride + sgl;
  const u16* vstg = vTbh + (size_t)(16 * wave + srow) * Tz + sgl;

  auto stage_issue = [&](int kt, int buf) {
#pragma unroll
    for (int c2 = 0; c2 < 2; ++c2) {
      gl_lds16(kstg + (size_t)(8 * c2) * rowstride + (size_t)(64 * kt) * rowstride,
               &KsL[buf][(16 * wave + 8 * c2) * 64]);
      gl_lds16(vstg + (size_t)(8 * c2) * Tz + 64 * kt,
               &VtL[buf][(16 * wave + 8 * c2) * 64]);
    }
  };

  stage_issue(0, 0);

  for (int kt = 0; kt <= qt; ++kt) {
    __syncthreads();
    const int cb = kt & 1;
    if (kt + 1 <= qt) stage_issue(kt + 1, 1 - cb);

    f32x4 S[4];
#pragma unroll
    for (int c = 0; c < 4; ++c) {
      const int rb = (16 * c + lm) * 64;
      bf16x8 k0 = *(const bf16x8*)&KsL[cb][rb + ((lg ^ (lm & 7)) << 3)];
      bf16x8 k1 = *(const bf16x8*)&KsL[cb][rb + (((lg + 4) ^ (lm & 7)) << 3)];
      f32x4 s;
#pragma unroll
      for (int i = 0; i < 4; ++i) s[i] = 0.f;
      s = MFMA32(k0, qf[0], s);
      s = MFMA32(k1, qf[1], s);
      S[c] = s;
    }

    const bool diag = (kt == qt);
    const int qloc = 16 * wave + lm;
    bf16x4 pf[4];
#pragma unroll
    for (int c = 0; c < 4; ++c) {
#pragma unroll
      for (int r = 0; r < 4; ++r) {
        float p = fexp2(S[c][r]);
        if (diag && (c * 16 + 4 * lg + r) > qloc) p = 0.f;
        psum += p;
        pf[c][r] = (short)f2bf(p);
      }
    }

#pragma unroll
    for (int dt = 0; dt < 4; ++dt) {
      const int rb = (16 * dt + lm) * 64;
#pragma unroll
      for (int c = 0; c < 4; ++c) {
        const int off = (((2 * c + (lg >> 1)) ^ (lm & 7)) << 3) + 4 * (lg & 1);
        bf16x4 vfr = *(const bf16x4*)&VtL[cb][rb + off];
        Oa[dt] = mfma16(pf[c], vfr, Oa[dt]);
      }
    }
  }

  float s = psum;
  s += __shfl_xor(s, 16);
  s += __shfl_xor(s, 32);
  const float linv = 1.f / s;
  float invq[4];
#pragma unroll
  for (int r = 0; r < 4; ++r)
    invq[r] = __shfl(linv, 20 * lg + r);
  __syncthreads();
#pragma unroll
  for (int dt = 0; dt < 4; ++dt)
#pragma unroll
    for (int r = 0; r < 4; ++r)
      KsL[0][(16 * wave + 4 * lg + r) * 64 + 16 * dt + lm] =
          f2bf(Oa[dt][r] * invq[r]);
  __syncthreads();
  {
    const int row = lane >> 2, seg = lane & 3;
    const uint4* src = (const uint4*)&KsL[0][(16 * wave + row) * 64 + seg * 16];
    uint4 v0 = src[0];
    uint4 v1 = src[1];
    u16* dst = yb + (size_t)(b * Tz + q0 + 16 * wave + row) * Cz + h * Dz + seg * 16;
    *(uint4*)dst = v0;
    *(uint4*)(dst + 8) = v1;
  }
}

extern "C" void kernel_launch(void* const* d_in, const int* in_sizes, int n_in,
                              void* d_out, int out_size, void* d_ws, size_t ws_size,
                              hipStream_t stream) {
  const float* x      = (const float*)d_in[0];
  const float* w_attn = (const float*)d_in[1];
  const float* b_attn = (const float*)d_in[2];
  const float* w_proj = (const float*)d_in[3];
  const float* b_proj = (const float*)d_in[4];

  char* ws = (char*)d_ws;
  u16* xb   = (u16*)(ws);                        //  8 MB: x bf16 [4096,1024]
  u16* waT  = (u16*)(ws + (8ull << 20));         //  6 MB: w_attn^T bf16 [3072,1024]
  u16* wpT  = (u16*)(ws + (14ull << 20));        //  2 MB: w_proj^T bf16 [1024,1024]
  u16* qkvb = (u16*)(ws + (16ull << 20));        // 24 MB: qkv bf16 (q pre-scaled; V cols unused)
  u16* yb   = (u16*)(ws + (40ull << 20));        //  8 MB: y bf16 [4096,1024]
  u16* vTt  = (u16*)(ws + (48ull << 20));        //  8 MB: V^T bf16 [2*16*64][2048]

  const int M = Bz * Tz;  // 4096

  prep_kernel<<<NCAST + NTA + 1024, 256, 0, stream>>>(x, w_attn, w_proj, xb, waT, wpT);
  gemm_qkv<<<dim3(12, 16), 512, 0, stream>>>(xb, waT, b_attn, qkvb, vTt);
  attn_kernel<<<1024, 256, 0, stream>>>(qkvb, vTt, yb);
  gemm_bt<false, 64, false><<<dim3(Cz / 64, M / 128), 256, 0, stream>>>(
      yb, wpT, b_proj, d_out, nullptr, M, Cz, Cz, 0, 1.f);
}